// Round 5
// baseline (2236.565 us; speedup 1.0000x reference)
//
#include <hip/hip_runtime.h>
#include <stdint.h>

typedef __attribute__((ext_vector_type(8))) short short8;
typedef __attribute__((ext_vector_type(4))) float f32x4;
typedef __attribute__((ext_vector_type(4))) unsigned int uint32x4;
typedef __attribute__((ext_vector_type(2))) unsigned int uint32x2;
typedef unsigned int uint32;
typedef unsigned short ushort16;

#define SEQ 512
#define BATCH 128
#define DIN 512
#define DH 1024
#define DOUT 256

// ---- workspace layout (bytes) ----
#define XW_OFF   0u
#define XW_BYTES 134217728u            // 65536*1024*2 (bf16 xW)
#define WH_OFF   (XW_OFF + XW_BYTES)
#define WH_BYTES 2097152u              // 1024*1024 bf16 (N x K row-major)
#define WX_OFF   (WH_OFF + WH_BYTES)
#define WX_BYTES 1048576u              // 1024*512 bf16
#define HB_OFF   (WX_OFF + WX_BYTES)
#define HB_BYTES 1048576u              // 2 x 128 x 512 cells x 8B (value+seq)
#define DN_OFF   (HB_OFF + HB_BYTES)
#define DN_BYTES 262144u               // hint flags: 8 groups x 64 waves

__device__ __forceinline__ ushort16 f2bf(float f) {
  uint32 u = __float_as_uint(f);
  u = u + 0x7fffu + ((u >> 16) & 1u);
  return (ushort16)(u >> 16);
}
__device__ __forceinline__ float bf2f(ushort16 h) {
  return __uint_as_float(((uint32)h) << 16);
}
__device__ __forceinline__ uint32 packbf(float lo, float hi) {
  return (uint32)f2bf(lo) | ((uint32)f2bf(hi) << 16);
}
__device__ __forceinline__ float tanh_fast(float x) {
  float e = __expf(2.0f * x);
  return 1.0f - 2.0f / (e + 1.0f);
}

// ---------------------------------------------------------------------------
// K0: convert weights to bf16, pack+stamp h0 (seq=0), zero hint flags
// ---------------------------------------------------------------------------
__global__ __launch_bounds__(256) void prep_kernel(
    const float* __restrict__ W_i2h, const float* __restrict__ hidden,
    ushort16* __restrict__ Wx, ushort16* __restrict__ Wh,
    uint32x2* __restrict__ hpair, uint32* __restrict__ flags) {
  int idx = blockIdx.x * 256 + threadIdx.x;
  if (idx < DH * (DIN + DH)) {
    int row = idx / (DIN + DH);
    int col = idx - row * (DIN + DH);
    float v = W_i2h[idx];
    if (col < DIN) Wx[row * DIN + col] = f2bf(v);
    else           Wh[row * DH + (col - DIN)] = f2bf(v);
  }
  if (idx < BATCH * (DH / 2)) {        // 65536 cells: stamp h0 into buffer 0
    int b = idx >> 9, dk = idx & 511;
    hpair[idx] = (uint32x2){packbf(hidden[b * DH + dk * 2], hidden[b * DH + dk * 2 + 1]), 0u};
  }
  if (idx < 65536) flags[idx] = 0u;
  // buffer 1 stays poisoned (0xAA..) — validation compares seq == t exactly,
  // and 0xAAAAAAAA never equals any t in [0,512].
}

// ---------------------------------------------------------------------------
// K1: xW = x @ Wx^T  (M=65536, N=1024, K=512), bf16 in/out, fp32 accum
// ---------------------------------------------------------------------------
__global__ __launch_bounds__(256) void xw_gemm_kernel(
    const float* __restrict__ x, const ushort16* __restrict__ Wx,
    ushort16* __restrict__ xw) {
  __shared__ __attribute__((aligned(16))) ushort16 Al[128 * 72];
  __shared__ __attribute__((aligned(16))) ushort16 Bl[128 * 72];
  const int tid = threadIdx.x;
  const int lane = tid & 63;
  const int wv = tid >> 6;
  const int mh = wv & 1, nh = wv >> 1;
  const int bm = blockIdx.x >> 3;
  const int bn = blockIdx.x & 7;

  f32x4 acc[4][4];
#pragma unroll
  for (int i = 0; i < 4; ++i)
#pragma unroll
    for (int j = 0; j < 4; ++j) acc[i][j] = (f32x4){0.f, 0.f, 0.f, 0.f};

  uint32* Al32 = (uint32*)Al;

  for (int ko = 0; ko < DIN; ko += 64) {
#pragma unroll
    for (int i = 0; i < 8; ++i) {
      int linear = i * 256 + tid;
      int row = linear >> 4, c4 = linear & 15;
      const float4 v = *(const float4*)(x + (size_t)(bm * 128 + row) * DIN + ko + c4 * 4);
      uint2 p;
      p.x = packbf(v.x, v.y);
      p.y = packbf(v.z, v.w);
      *(uint2*)(Al32 + row * 36 + c4 * 2) = p;
    }
#pragma unroll
    for (int i = 0; i < 4; ++i) {
      int linear = i * 256 + tid;
      int row = linear >> 3, c8 = linear & 7;
      short8 v = *(const short8*)(Wx + (size_t)(bn * 128 + row) * DIN + ko + c8 * 8);
      *(short8*)(Bl + row * 72 + c8 * 8) = v;
    }
    __syncthreads();
#pragma unroll
    for (int kk = 0; kk < 64; kk += 32) {
      short8 af[4], bfv[4];
      const int kb = kk + ((lane >> 4) * 8);
#pragma unroll
      for (int mt = 0; mt < 4; ++mt)
        af[mt] = *(const short8*)(Al + (mh * 64 + mt * 16 + (lane & 15)) * 72 + kb);
#pragma unroll
      for (int nt = 0; nt < 4; ++nt)
        bfv[nt] = *(const short8*)(Bl + (nh * 64 + nt * 16 + (lane & 15)) * 72 + kb);
#pragma unroll
      for (int mt = 0; mt < 4; ++mt)
#pragma unroll
        for (int nt = 0; nt < 4; ++nt)
          acc[mt][nt] = __builtin_amdgcn_mfma_f32_16x16x32_bf16(af[mt], bfv[nt], acc[mt][nt], 0, 0, 0);
    }
    __syncthreads();
  }
#pragma unroll
  for (int mt = 0; mt < 4; ++mt)
#pragma unroll
    for (int nt = 0; nt < 4; ++nt)
#pragma unroll
      for (int r = 0; r < 4; ++r) {
        float v = acc[mt][nt][r];
        float o = __shfl_xor(v, 1);
        if (!(lane & 1)) {
          int m = bm * 128 + mh * 64 + mt * 16 + ((lane >> 4) * 4) + r;
          int c = bn * 128 + nh * 64 + nt * 16 + (lane & 15);
          ((uint32*)xw)[(size_t)m * 512 + (c >> 1)] = packbf(v, o);
        }
      }
}

// ---------------------------------------------------------------------------
// K2: recurrence. 128 blocks = 8 groups (blockIdx%8) x 16 blocks.
// h exchanged as SELF-STAMPED 8B cells {bf16x2 value, seq} via single
// dwordx2 stores: the stamp rides in the same store as the data, so there is
// NO producer-side drain and NO ordered flag. Flags are unordered HINTS only;
// the stage pass validates per-cell seq == t-1 and retries (rarely) until
// fresh. Buffer-reuse safety: producer reaches step t's writes only after
// staging all of h_{t-1}, which requires every wave's publishes of t-1, which
// retire only after their reads of h_{t-2} — so no cell is overwritten while
// a consumer still needs/polls it, and seq progresses s-2 -> s monotonically.
// ---------------------------------------------------------------------------
__global__ __launch_bounds__(256, 1) void rnn_kernel(
    const ushort16* __restrict__ xw, const ushort16* __restrict__ Wh,
    const float* __restrict__ b_i2h,
    uint32x2* hpair, uint32* flags, float* __restrict__ h_out) {
  const int g = blockIdx.x & 7;
  const int w = blockIdx.x >> 3;          // 0..15
  const int tid = threadIdx.x;
  const int lane = tid & 63;
  const int q = tid >> 6;                 // wave 0..3
  const int bcol = w * 64 + q * 16 + (lane & 15);
  const int rowloc = (lane >> 4) * 4;     // 0,4,8,12

  __shared__ __attribute__((aligned(16))) ushort16 h_lds[16 * 1032]; // row stride 2064B

  // Wh fragments: 16-col tile x full K. Pinned via "+v" asm each iteration
  // (round 4: compiler carries them in AGPRs; MFMA reads AGPR directly).
  short8 bfrag[32];
#pragma unroll
  for (int ks = 0; ks < 32; ++ks)
    bfrag[ks] = *(const short8*)(Wh + (size_t)bcol * DH + ks * 32 + ((lane >> 4) * 8));
  const float biasv = b_i2h[bcol];
  uint32* hl32 = (uint32*)h_lds;
  uint32* fgrp = flags + g * 64;
  const int myflag = w * 4 + q;

  // stage addressing: pair index p = tid + 256*j (j=0..15) over 4096 pairs;
  // cell = 2 consecutive cols; global byte offset = p*16 (dwordx4 = 2 cells)
  uint32 voffp[16];
#pragma unroll
  for (int j = 0; j < 16; ++j) voffp[j] = (uint32)((tid + 256 * j) * 16);
  const uint32x2* pg0 = hpair + (size_t)g * 16 * 512;           // buffer 0 group base
  const uint32x2* pg1 = hpair + 65536 + (size_t)g * 16 * 512;   // buffer 1 group base

  for (int t = 1; t <= SEQ; ++t) {
    const int s = t - 1;
    // PIN Wh fragments (see round-4 note)
    asm volatile("" : "+v"(bfrag[0]), "+v"(bfrag[1]), "+v"(bfrag[2]), "+v"(bfrag[3]),
                      "+v"(bfrag[4]), "+v"(bfrag[5]), "+v"(bfrag[6]), "+v"(bfrag[7]),
                      "+v"(bfrag[8]), "+v"(bfrag[9]), "+v"(bfrag[10]), "+v"(bfrag[11]),
                      "+v"(bfrag[12]), "+v"(bfrag[13]), "+v"(bfrag[14]), "+v"(bfrag[15]));
    asm volatile("" : "+v"(bfrag[16]), "+v"(bfrag[17]), "+v"(bfrag[18]), "+v"(bfrag[19]),
                      "+v"(bfrag[20]), "+v"(bfrag[21]), "+v"(bfrag[22]), "+v"(bfrag[23]),
                      "+v"(bfrag[24]), "+v"(bfrag[25]), "+v"(bfrag[26]), "+v"(bfrag[27]),
                      "+v"(bfrag[28]), "+v"(bfrag[29]), "+v"(bfrag[30]), "+v"(bfrag[31]));

    // xW prefetch (independent of h; overlaps the hint poll)
    float xwv[4];
#pragma unroll
    for (int r = 0; r < 4; ++r)
      xwv[r] = bf2f(xw[(size_t)(s * BATCH + g * 16 + rowloc + r) * DH + bcol]);

    // hint poll: cheap wait until all 64 waves *probably* published h_{t-1}
    if (t > 1) {
      const uint32 need = (uint32)(t - 1);
      for (;;) {
        uint32 v = __hip_atomic_load(fgrp + lane, __ATOMIC_RELAXED, __HIP_MEMORY_SCOPE_AGENT);
        if (__ballot(v >= need) == ~0ull) break;
      }
    }

    // validated stage: load 16 x dwordx4 (2 stamped cells each), retry until
    // every seq field == s. Per-lane exit (exec-masked retries).
    {
      const uint32x2* hsrc = (s & 1) ? pg1 : pg0;
      const uint32 su = (uint32)s;
      uint32x4 rb[16];
      for (;;) {
        asm volatile(
            "global_load_dwordx4 %0, %16, %32 sc0 sc1\n\t"
            "global_load_dwordx4 %1, %17, %32 sc0 sc1\n\t"
            "global_load_dwordx4 %2, %18, %32 sc0 sc1\n\t"
            "global_load_dwordx4 %3, %19, %32 sc0 sc1\n\t"
            "global_load_dwordx4 %4, %20, %32 sc0 sc1\n\t"
            "global_load_dwordx4 %5, %21, %32 sc0 sc1\n\t"
            "global_load_dwordx4 %6, %22, %32 sc0 sc1\n\t"
            "global_load_dwordx4 %7, %23, %32 sc0 sc1\n\t"
            "global_load_dwordx4 %8, %24, %32 sc0 sc1\n\t"
            "global_load_dwordx4 %9, %25, %32 sc0 sc1\n\t"
            "global_load_dwordx4 %10, %26, %32 sc0 sc1\n\t"
            "global_load_dwordx4 %11, %27, %32 sc0 sc1\n\t"
            "global_load_dwordx4 %12, %28, %32 sc0 sc1\n\t"
            "global_load_dwordx4 %13, %29, %32 sc0 sc1\n\t"
            "global_load_dwordx4 %14, %30, %32 sc0 sc1\n\t"
            "global_load_dwordx4 %15, %31, %32 sc0 sc1\n\t"
            "s_waitcnt vmcnt(0)"
            : "=&v"(rb[0]), "=&v"(rb[1]), "=&v"(rb[2]), "=&v"(rb[3]),
              "=&v"(rb[4]), "=&v"(rb[5]), "=&v"(rb[6]), "=&v"(rb[7]),
              "=&v"(rb[8]), "=&v"(rb[9]), "=&v"(rb[10]), "=&v"(rb[11]),
              "=&v"(rb[12]), "=&v"(rb[13]), "=&v"(rb[14]), "=&v"(rb[15])
            : "v"(voffp[0]), "v"(voffp[1]), "v"(voffp[2]), "v"(voffp[3]),
              "v"(voffp[4]), "v"(voffp[5]), "v"(voffp[6]), "v"(voffp[7]),
              "v"(voffp[8]), "v"(voffp[9]), "v"(voffp[10]), "v"(voffp[11]),
              "v"(voffp[12]), "v"(voffp[13]), "v"(voffp[14]), "v"(voffp[15]),
              "s"(hsrc)
            : "memory");
        uint32 bad = 0;
#pragma unroll
        for (int j = 0; j < 16; ++j)
          bad |= (rb[j][1] ^ su) | (rb[j][3] ^ su);
        if (bad == 0) break;
      }
#pragma unroll
      for (int j = 0; j < 16; ++j) {
        int p = tid + 256 * j;
        *(uint32x2*)(hl32 + (p >> 8) * 516 + (p & 255) * 2) =
            (uint32x2){rb[j][0], rb[j][2]};
      }
    }
    __syncthreads();

    // h @ Wh, full K=1024; four independent accumulator chains
    f32x4 acc0 = (f32x4){0.f, 0.f, 0.f, 0.f};
    f32x4 acc1 = (f32x4){0.f, 0.f, 0.f, 0.f};
    f32x4 acc2 = (f32x4){0.f, 0.f, 0.f, 0.f};
    f32x4 acc3 = (f32x4){0.f, 0.f, 0.f, 0.f};
#pragma unroll
    for (int ks = 0; ks < 8; ++ks) {
      const char* base = (const char*)h_lds + (lane & 15) * 2064 + ((lane >> 4) * 16);
      short8 af0 = *(const short8*)(base + (4 * ks + 0) * 64);
      short8 af1 = *(const short8*)(base + (4 * ks + 1) * 64);
      short8 af2 = *(const short8*)(base + (4 * ks + 2) * 64);
      short8 af3 = *(const short8*)(base + (4 * ks + 3) * 64);
      acc0 = __builtin_amdgcn_mfma_f32_16x16x32_bf16(af0, bfrag[4 * ks + 0], acc0, 0, 0, 0);
      acc1 = __builtin_amdgcn_mfma_f32_16x16x32_bf16(af1, bfrag[4 * ks + 1], acc1, 0, 0, 0);
      acc2 = __builtin_amdgcn_mfma_f32_16x16x32_bf16(af2, bfrag[4 * ks + 2], acc2, 0, 0, 0);
      acc3 = __builtin_amdgcn_mfma_f32_16x16x32_bf16(af3, bfrag[4 * ks + 3], acc3, 0, 0, 0);
    }

    float hv[4];
#pragma unroll
    for (int r = 0; r < 4; ++r)
      hv[r] = tanh_fast((acc0[r] + acc1[r]) + (acc2[r] + acc3[r]) + biasv + xwv[r]);

    // publish h_t: stamped 8B cells, NO drain; then hint flag (unordered)
    {
      uint32x2* hdst = (uint32x2*)((t & 1) ? pg1 : pg0);
#pragma unroll
      for (int r = 0; r < 4; ++r) {
        float o = __shfl_xor(hv[r], 1);
        uint32x2 val = {packbf(hv[r], o), (uint32)t};
        if (!(lane & 1)) {
          uint32x2* p = hdst + (size_t)(rowloc + r) * 512 + (bcol >> 1);
          asm volatile("global_store_dwordx2 %0, %1, off sc0 sc1"
                       :: "v"(p), "v"(val) : "memory");
        }
      }
    }
    if (t == SEQ) {
#pragma unroll
      for (int r = 0; r < 4; ++r)
        h_out[(size_t)(g * 16 + rowloc + r) * DH + bcol] = hv[r];
    }
    if (lane == 0) {
      uint32* fp = fgrp + myflag;
      uint32 tv = (uint32)t;
      asm volatile("global_store_dword %0, %1, off sc0 sc1"
                   :: "v"(fp), "v"(tv) : "memory");
    }
  }
}

// ---------------------------------------------------------------------------
// K3: logits = h_final @ W_h2o^T + b; row softmax. 1 block per batch row.
// ---------------------------------------------------------------------------
__global__ __launch_bounds__(256) void head_kernel(
    const float* __restrict__ hfin, const float* __restrict__ W,
    const float* __restrict__ bias, float* __restrict__ out) {
  __shared__ __attribute__((aligned(16))) float hrow[DH];
  __shared__ float rbuf[256];
  const int b = blockIdx.x;
  const int tid = threadIdx.x;
  for (int i = tid; i < DH; i += 256) hrow[i] = hfin[(size_t)b * DH + i];
  __syncthreads();
  float s = bias[tid];
  const float4* wr = (const float4*)(W + (size_t)tid * DH);
#pragma unroll 4
  for (int k = 0; k < DH / 4; ++k) {
    float4 wv = wr[k];
    float4 hv = *(const float4*)(hrow + k * 4);
    s += wv.x * hv.x + wv.y * hv.y + wv.z * hv.z + wv.w * hv.w;
  }
  rbuf[tid] = s;
  __syncthreads();
  for (int off = 128; off > 0; off >>= 1) {
    if (tid < off) rbuf[tid] = fmaxf(rbuf[tid], rbuf[tid + off]);
    __syncthreads();
  }
  float mx = rbuf[0];
  __syncthreads();
  float e = __expf(s - mx);
  rbuf[tid] = e;
  __syncthreads();
  for (int off = 128; off > 0; off >>= 1) {
    if (tid < off) rbuf[tid] += rbuf[tid + off];
    __syncthreads();
  }
  out[(size_t)b * DOUT + tid] = e / rbuf[0];
}

// ---------------------------------------------------------------------------
extern "C" void kernel_launch(void* const* d_in, const int* in_sizes, int n_in,
                              void* d_out, int out_size, void* d_ws, size_t ws_size,
                              hipStream_t stream) {
  const float* x      = (const float*)d_in[0];
  const float* hidden = (const float*)d_in[1];
  const float* W_i2h  = (const float*)d_in[2];
  const float* b_i2h  = (const float*)d_in[3];
  const float* W_h2o  = (const float*)d_in[4];
  const float* b_h2o  = (const float*)d_in[5];
  float* out = (float*)d_out;

  char* ws = (char*)d_ws;
  ushort16* xw    = (ushort16*)(ws + XW_OFF);
  ushort16* Wh    = (ushort16*)(ws + WH_OFF);
  ushort16* Wx    = (ushort16*)(ws + WX_OFF);
  uint32x2* hpair = (uint32x2*)(ws + HB_OFF);
  uint32*   flags = (uint32*)(ws + DN_OFF);

  prep_kernel<<<6144, 256, 0, stream>>>(W_i2h, hidden, Wx, Wh, hpair, flags);
  xw_gemm_kernel<<<4096, 256, 0, stream>>>(x, Wx, xw);
  rnn_kernel<<<128, 256, 0, stream>>>(xw, Wh, b_i2h, hpair, flags, out + BATCH * DOUT);
  head_kernel<<<128, 256, 0, stream>>>(out + BATCH * DOUT, W_h2o, b_h2o, out);
}